// Round 3
// baseline (589.415 us; speedup 1.0000x reference)
//
#include <hip/hip_runtime.h>
#include <hip/hip_bf16.h>

typedef __hip_bfloat16 bf16;
typedef __attribute__((ext_vector_type(8))) short short8;
typedef __attribute__((ext_vector_type(8))) unsigned short ushort8;
typedef __attribute__((ext_vector_type(4))) float floatx4;

#define BATCH 2
#define S_LEN 2048
#define NHEAD 16
#define HD 128
#define HIDDEN 2048

static __device__ __forceinline__ unsigned short f2bf(float f) {
    union { float f; unsigned int u; } c; c.f = f;
    unsigned int u = c.u;
    unsigned int rounded = u + 0x7FFF + ((u >> 16) & 1);   // RNE
    return (unsigned short)(rounded >> 16);
}

// ---------------------------------------------------------------------------
// Elementwise cast fp32 -> bf16, 8 elements/thread
// ---------------------------------------------------------------------------
__global__ __launch_bounds__(256) void cast_f32_bf16(const float* __restrict__ src,
                                                     bf16* __restrict__ dst) {
    int i = (blockIdx.x * 256 + threadIdx.x) * 8;
    float4 a = *(const float4*)&src[i];
    float4 b = *(const float4*)&src[i + 4];
    ushort8 o;
    o[0] = f2bf(a.x); o[1] = f2bf(a.y); o[2] = f2bf(a.z); o[3] = f2bf(a.w);
    o[4] = f2bf(b.x); o[5] = f2bf(b.y); o[6] = f2bf(b.z); o[7] = f2bf(b.w);
    *(ushort8*)&dst[i] = o;
}

// ---------------------------------------------------------------------------
// Cast+transpose: dst[C x R] (bf16) = src[R x C]^T (fp32)
// ---------------------------------------------------------------------------
__global__ __launch_bounds__(256) void cast_transpose(const float* __restrict__ src,
                                                      bf16* __restrict__ dst,
                                                      int R, int C) {
    __shared__ unsigned short t[32][33];
    int tx = threadIdx.x & 31, ty = threadIdx.x >> 5;  // 32 x 8
    int c0 = blockIdx.x * 32, r0 = blockIdx.y * 32;
#pragma unroll
    for (int i = 0; i < 4; i++) {
        int r = r0 + ty + i * 8;
        t[ty + i * 8][tx] = f2bf(src[(size_t)r * C + c0 + tx]);
    }
    __syncthreads();
#pragma unroll
    for (int i = 0; i < 4; i++) {
        int cc = c0 + ty + i * 8;
        ((unsigned short*)dst)[(size_t)cc * R + r0 + tx] = t[tx][ty + i * 8];
    }
}

// ---------------------------------------------------------------------------
// GEMM: C[M x N] = A[M x K] * Bt[N x K]^T + bias  (128x128 tile, bf16 MFMA)
// mode 0: scatter into Qb/Kb (b,h,s,d) and Vt (b,h,d,s)   (N = 6144)
// mode 1: plain fp32 store to C                            (N = 2048)
// ---------------------------------------------------------------------------
__global__ __launch_bounds__(256) void gemm_bt(const bf16* __restrict__ A,
                                               const bf16* __restrict__ Bt,
                                               const float* __restrict__ bias,
                                               float* __restrict__ C,
                                               bf16* __restrict__ Qb,
                                               bf16* __restrict__ Kb,
                                               bf16* __restrict__ Vt,
                                               int M, int N, int K, int mode) {
    __shared__ __align__(16) bf16 As[128 * 32];
    __shared__ __align__(16) bf16 Bs[128 * 32];

    int tid = threadIdx.x;
    int wave = tid >> 6, lane = tid & 63;
    int quad = lane >> 4, lr = lane & 15;
    int wm = wave >> 1, wn = wave & 1;
    int m0 = blockIdx.y * 128, n0 = blockIdx.x * 128;

    const floatx4 fzero = {0.f, 0.f, 0.f, 0.f};
    floatx4 acc[4][4];
#pragma unroll
    for (int i = 0; i < 4; i++)
#pragma unroll
        for (int j = 0; j < 4; j++) acc[i][j] = fzero;

    for (int kt = 0; kt < K; kt += 32) {
        ushort8 va[2], vb[2];
#pragma unroll
        for (int i = 0; i < 2; i++) {
            int idx = tid * 2 + i;            // 0..511
            int r = idx >> 2, c8 = (idx & 3) * 8;
            va[i] = *(const ushort8*)&A[(size_t)(m0 + r) * K + kt + c8];
            vb[i] = *(const ushort8*)&Bt[(size_t)(n0 + r) * K + kt + c8];
        }
        __syncthreads();  // previous iteration's LDS reads done
#pragma unroll
        for (int i = 0; i < 2; i++) {
            int idx = tid * 2 + i;
            *(ushort8*)&As[idx * 8] = va[i];  // row-major [128][32]
            *(ushort8*)&Bs[idx * 8] = vb[i];
        }
        __syncthreads();

        short8 aF[4], bF[4];
#pragma unroll
        for (int i = 0; i < 4; i++)
            aF[i] = *(const short8*)(As + (wm * 64 + i * 16 + lr) * 32 + quad * 8);
#pragma unroll
        for (int j = 0; j < 4; j++)
            bF[j] = *(const short8*)(Bs + (wn * 64 + j * 16 + lr) * 32 + quad * 8);
#pragma unroll
        for (int i = 0; i < 4; i++)
#pragma unroll
            for (int j = 0; j < 4; j++)
                acc[i][j] = __builtin_amdgcn_mfma_f32_16x16x32_bf16(aF[i], bF[j], acc[i][j], 0, 0, 0);
    }

    // epilogue: C/D layout col(n) = lane&15, row(m) = quad*4 + reg
#pragma unroll
    for (int i = 0; i < 4; i++) {
#pragma unroll
        for (int j = 0; j < 4; j++) {
            int gcn = n0 + wn * 64 + j * 16 + lr;
            float bv = bias[gcn];
#pragma unroll
            for (int reg = 0; reg < 4; reg++) {
                int gm = m0 + wm * 64 + i * 16 + quad * 4 + reg;
                float v = acc[i][j][reg] + bv;
                if (mode == 0) {
                    bf16 o = __float2bfloat16(v);
                    int t = gcn >> 11, hh = (gcn >> 7) & 15, d = gcn & 127;
                    int bb = gm >> 11, s = gm & 2047;
                    size_t hb = (size_t)(bb * NHEAD + hh);
                    if (t == 0)      Qb[(hb * S_LEN + s) * HD + d] = o;
                    else if (t == 1) Kb[(hb * S_LEN + s) * HD + d] = o;
                    else             Vt[(hb * HD + d) * S_LEN + s] = o;
                } else {
                    C[(size_t)gm * N + gcn] = v;
                }
            }
        }
    }
}

// ---------------------------------------------------------------------------
// Flash attention (causal). Block = 4 waves x 64. Q-tile = 128 rows (32/wave).
// K/V tiles of 64 key positions. Q:[b,h,s,d] K:[b,h,s,d] Vt:[b,h,d,s]
// Output Obuf: [b*s][h*d]  (GEMM2 A-matrix, bf16)
// ---------------------------------------------------------------------------
__global__ __launch_bounds__(256) void attn_kernel(const bf16* __restrict__ Qb,
                                                   const bf16* __restrict__ Kb,
                                                   const bf16* __restrict__ Vt,
                                                   bf16* __restrict__ Obuf) {
    __shared__ __align__(16) bf16 Ks[64][136];     // [k_local][d] pad 8
    __shared__ __align__(16) bf16 Vs[128][72];     // [d][k_local] pad 8
    __shared__ __align__(16) bf16 Ps[4][32][72];   // per-wave P tile

    int tid = threadIdx.x;
    int wave = tid >> 6, lane = tid & 63;
    int quad = lane >> 4, lr = lane & 15;
    int qt = blockIdx.x, head = blockIdx.y, b = blockIdx.z;
    int q0 = qt * 128;
    size_t hb = (size_t)(b * NHEAD + head);
    const bf16* Qbase = Qb + hb * S_LEN * HD;
    const bf16* Kbase = Kb + hb * S_LEN * HD;
    const bf16* Vbase = Vt + hb * (size_t)HD * S_LEN;

    // Q fragments in registers: A-layout, rows = q0 + wave*32 + mt*16 + lr
    short8 qF[2][4];
#pragma unroll
    for (int mt = 0; mt < 2; mt++)
#pragma unroll
        for (int kc = 0; kc < 4; kc++)
            qF[mt][kc] = *(const short8*)&Qbase[(size_t)(q0 + wave * 32 + mt * 16 + lr) * HD + kc * 32 + quad * 8];

    const floatx4 fzero = {0.f, 0.f, 0.f, 0.f};
    floatx4 Oacc[2][8];
    float mrow[2][4], lrow[2][4];
#pragma unroll
    for (int mt = 0; mt < 2; mt++) {
#pragma unroll
        for (int dn = 0; dn < 8; dn++) Oacc[mt][dn] = fzero;
#pragma unroll
        for (int r = 0; r < 4; r++) { mrow[mt][r] = -30000.f; lrow[mt][r] = 0.f; }
    }

    const float k2 = 0.08838834764831845f * 1.4426950408889634f;  // 1/sqrt(128)*log2(e)
    const float MASKV = -30000.f;
    int nkt = qt * 2 + 2;
    int qlast = q0 + wave * 32 + 31;

    for (int kt = 0; kt < nkt; kt++) {
        int ks0 = kt * 64;
        __syncthreads();
        {
            const bf16* Kt = Kbase + (size_t)ks0 * HD;
#pragma unroll
            for (int i = 0; i < 4; i++) {
                int c = tid + i * 256;        // 0..1023
                int r = c >> 4, col = (c & 15) * 8;
                *(ushort8*)&Ks[r][col] = *(const ushort8*)&Kt[r * HD + col];
            }
#pragma unroll
            for (int i = 0; i < 4; i++) {
                int c = tid + i * 256;
                int r = c >> 3, col = (c & 7) * 8;
                *(ushort8*)&Vs[r][col] = *(const ushort8*)&Vbase[(size_t)r * S_LEN + ks0 + col];
            }
        }
        __syncthreads();

        if (ks0 <= qlast) {
            // QK^T: S[m=q][n=k_local], contraction over d (4 x 32)
            floatx4 sc[2][4];
#pragma unroll
            for (int mt = 0; mt < 2; mt++)
#pragma unroll
                for (int nt = 0; nt < 4; nt++) sc[mt][nt] = fzero;
#pragma unroll
            for (int kc = 0; kc < 4; kc++)
#pragma unroll
                for (int nt = 0; nt < 4; nt++) {
                    short8 kf = *(const short8*)&Ks[nt * 16 + lr][kc * 32 + quad * 8];
#pragma unroll
                    for (int mt = 0; mt < 2; mt++)
                        sc[mt][nt] = __builtin_amdgcn_mfma_f32_16x16x32_bf16(qF[mt][kc], kf, sc[mt][nt], 0, 0, 0);
                }
            // scale + causal mask (keep key <= query)
#pragma unroll
            for (int mt = 0; mt < 2; mt++)
#pragma unroll
                for (int nt = 0; nt < 4; nt++)
#pragma unroll
                    for (int reg = 0; reg < 4; reg++) {
                        int qg = q0 + wave * 32 + mt * 16 + quad * 4 + reg;
                        int kg = ks0 + nt * 16 + lr;
                        float v = sc[mt][nt][reg] * k2;
                        sc[mt][nt][reg] = (kg > qg) ? MASKV : v;
                    }
            // online softmax per m-tile
#pragma unroll
            for (int mt = 0; mt < 2; mt++) {
                float pm[4], alpha[4], rs[4];
#pragma unroll
                for (int r = 0; r < 4; r++) {
                    pm[r] = sc[mt][0][r];
#pragma unroll
                    for (int nt = 1; nt < 4; nt++) pm[r] = fmaxf(pm[r], sc[mt][nt][r]);
                }
#pragma unroll
                for (int off = 1; off < 16; off <<= 1)
#pragma unroll
                    for (int r = 0; r < 4; r++) pm[r] = fmaxf(pm[r], __shfl_xor(pm[r], off, 64));
#pragma unroll
                for (int r = 0; r < 4; r++) {
                    float mn = fmaxf(mrow[mt][r], pm[r]);
                    alpha[r] = exp2f(mrow[mt][r] - mn);
                    mrow[mt][r] = mn;
                    rs[r] = 0.f;
                }
#pragma unroll
                for (int nt = 0; nt < 4; nt++)
#pragma unroll
                    for (int r = 0; r < 4; r++) {
                        float p = exp2f(sc[mt][nt][r] - mrow[mt][r]);
                        rs[r] += p;
                        Ps[wave][mt * 16 + quad * 4 + r][nt * 16 + lr] = __float2bfloat16(p);
                    }
#pragma unroll
                for (int off = 1; off < 16; off <<= 1)
#pragma unroll
                    for (int r = 0; r < 4; r++) rs[r] += __shfl_xor(rs[r], off, 64);
#pragma unroll
                for (int r = 0; r < 4; r++) lrow[mt][r] = lrow[mt][r] * alpha[r] + rs[r];
#pragma unroll
                for (int dn = 0; dn < 8; dn++)
#pragma unroll
                    for (int r = 0; r < 4; r++) Oacc[mt][dn][r] *= alpha[r];
            }
            // PV: O[m=q][n=d] += P[m][k=s_local] * V[k][n]; V from Vs[d][s]
#pragma unroll
            for (int st = 0; st < 2; st++) {
                short8 aP[2];
#pragma unroll
                for (int mt = 0; mt < 2; mt++)
                    aP[mt] = *(const short8*)&Ps[wave][mt * 16 + lr][st * 32 + quad * 8];
#pragma unroll
                for (int dn = 0; dn < 8; dn++) {
                    short8 vf = *(const short8*)&Vs[dn * 16 + lr][st * 32 + quad * 8];
#pragma unroll
                    for (int mt = 0; mt < 2; mt++)
                        Oacc[mt][dn] = __builtin_amdgcn_mfma_f32_16x16x32_bf16(aP[mt], vf, Oacc[mt][dn], 0, 0, 0);
                }
            }
        }
    }

    // epilogue: divide by l, store to Obuf[b*S+q][head*128+d]
#pragma unroll
    for (int mt = 0; mt < 2; mt++)
#pragma unroll
        for (int reg = 0; reg < 4; reg++) {
            float inv = 1.0f / lrow[mt][reg];
            int qg = q0 + wave * 32 + mt * 16 + quad * 4 + reg;
#pragma unroll
            for (int dn = 0; dn < 8; dn++) {
                int d = dn * 16 + lr;
                Obuf[((size_t)(b * S_LEN + qg)) * HIDDEN + head * HD + d] =
                    __float2bfloat16(Oacc[mt][dn][reg] * inv);
            }
        }
}

// ---------------------------------------------------------------------------
extern "C" void kernel_launch(void* const* d_in, const int* in_sizes, int n_in,
                              void* d_out, int out_size, void* d_ws, size_t ws_size,
                              hipStream_t stream) {
    (void)in_sizes; (void)n_in; (void)out_size; (void)ws_size;
    const float* x    = (const float*)d_in[0];   // (2,2048,2048) fp32
    const float* Wqkv = (const float*)d_in[1];   // (2048,6144)  fp32
    const float* bqkv = (const float*)d_in[2];   // (6144,)      fp32
    const float* Wo   = (const float*)d_in[3];   // (2048,2048)  fp32
    const float* bo   = (const float*)d_in[4];   // (2048,)      fp32
    float* out = (float*)d_out;                  // (2,2048,2048) fp32

    // Workspace (bf16 elements), 92.3 MB total with aliasing:
    //   Xb [4096*2048]  (aliased by Obuf after GEMM1)
    //   WqkvT [6144*2048]  (aliased by WoT after GEMM1)
    //   Qb, Kb, Vt [2*16*2048*128 each]
    bf16* ws = (bf16*)d_ws;
    bf16* Xb    = ws;                                   // 8.39M el
    bf16* Obuf  = ws;                                   // alias of Xb
    bf16* WqkvT = ws + (size_t)8388608;                 // 12.58M el
    bf16* WoT   = WqkvT;                                // alias (after GEMM1)
    bf16* Qb    = WqkvT + (size_t)12582912;
    bf16* Kb    = Qb + (size_t)8388608;
    bf16* Vt    = Kb + (size_t)8388608;

    cast_f32_bf16<<<4096, 256, 0, stream>>>(x, Xb);
    cast_transpose<<<dim3(192, 64), 256, 0, stream>>>(Wqkv, WqkvT, 2048, 6144);
    gemm_bt<<<dim3(48, 32), 256, 0, stream>>>(Xb, WqkvT, bqkv, nullptr,
                                              Qb, Kb, Vt, 4096, 6144, 2048, 0);
    cast_transpose<<<dim3(64, 64), 256, 0, stream>>>(Wo, WoT, 2048, 2048);
    attn_kernel<<<dim3(16, 16, 2), 256, 0, stream>>>(Qb, Kb, Vt, Obuf);
    gemm_bt<<<dim3(16, 32), 256, 0, stream>>>(Obuf, WoT, bo, out,
                                              nullptr, nullptr, nullptr, 4096, 2048, 2048, 1);
}

// Round 4
// 458.058 us; speedup vs baseline: 1.2868x; 1.2868x over previous
//
#include <hip/hip_runtime.h>
#include <hip/hip_bf16.h>

typedef __hip_bfloat16 bf16;
typedef __attribute__((ext_vector_type(8))) short short8;
typedef __attribute__((ext_vector_type(8))) unsigned short ushort8;
typedef __attribute__((ext_vector_type(4))) float floatx4;

#define BATCH 2
#define S_LEN 2048
#define NHEAD 16
#define HD 128
#define HIDDEN 2048
// softmax scale folded into Q at GEMM1 epilogue: 1/sqrt(128) * log2(e)
#define QSCALE 0.12754435f

static __device__ __forceinline__ unsigned short f2bf(float f) {
    union { float f; unsigned int u; } c; c.f = f;
    unsigned int u = c.u;
    unsigned int rounded = u + 0x7FFF + ((u >> 16) & 1);   // RNE
    return (unsigned short)(rounded >> 16);
}

// ---------------------------------------------------------------------------
// Elementwise cast fp32 -> bf16, 8 elements/thread
// ---------------------------------------------------------------------------
__global__ __launch_bounds__(256) void cast_f32_bf16(const float* __restrict__ src,
                                                     bf16* __restrict__ dst) {
    int i = (blockIdx.x * 256 + threadIdx.x) * 8;
    float4 a = *(const float4*)&src[i];
    float4 b = *(const float4*)&src[i + 4];
    ushort8 o;
    o[0] = f2bf(a.x); o[1] = f2bf(a.y); o[2] = f2bf(a.z); o[3] = f2bf(a.w);
    o[4] = f2bf(b.x); o[5] = f2bf(b.y); o[6] = f2bf(b.z); o[7] = f2bf(b.w);
    *(ushort8*)&dst[i] = o;
}

// ---------------------------------------------------------------------------
// Cast+transpose: dst[C x R] (bf16) = src[R x C]^T (fp32)
// ---------------------------------------------------------------------------
__global__ __launch_bounds__(256) void cast_transpose(const float* __restrict__ src,
                                                      bf16* __restrict__ dst,
                                                      int R, int C) {
    __shared__ unsigned short t[32][33];
    int tx = threadIdx.x & 31, ty = threadIdx.x >> 5;  // 32 x 8
    int c0 = blockIdx.x * 32, r0 = blockIdx.y * 32;
#pragma unroll
    for (int i = 0; i < 4; i++) {
        int r = r0 + ty + i * 8;
        t[ty + i * 8][tx] = f2bf(src[(size_t)r * C + c0 + tx]);
    }
    __syncthreads();
#pragma unroll
    for (int i = 0; i < 4; i++) {
        int cc = c0 + ty + i * 8;
        ((unsigned short*)dst)[(size_t)cc * R + r0 + tx] = t[tx][ty + i * 8];
    }
}

// ---------------------------------------------------------------------------
// GEMM: C = A[MxK] * Bt[NxK]^T + bias  (128x128 tile, global_load_lds staging)
// mode 0: scatter into Qb (pre-scaled by QSCALE) / Kb (b,h,s,d), Vt (b,h,d,s)
// mode 1: plain fp32 store to C
// ---------------------------------------------------------------------------
__global__ __launch_bounds__(256) void gemm_bt(const bf16* __restrict__ A,
                                               const bf16* __restrict__ Bt,
                                               const float* __restrict__ bias,
                                               float* __restrict__ C,
                                               bf16* __restrict__ Qb,
                                               bf16* __restrict__ Kb,
                                               bf16* __restrict__ Vt,
                                               int M, int N, int K, int mode) {
    __shared__ __align__(16) bf16 As[128 * 32];
    __shared__ __align__(16) bf16 Bs[128 * 32];

    int tid = threadIdx.x;
    int wave = tid >> 6, lane = tid & 63;
    int quad = lane >> 4, lr = lane & 15;
    int wm = wave >> 1, wn = wave & 1;
    int m0 = blockIdx.y * 128, n0 = blockIdx.x * 128;

    const floatx4 fzero = {0.f, 0.f, 0.f, 0.f};
    floatx4 acc[4][4];
#pragma unroll
    for (int i = 0; i < 4; i++)
#pragma unroll
        for (int j = 0; j < 4; j++) acc[i][j] = fzero;

    // staging: wave stages rows [wave*32, wave*32+32) of both tiles
    int rsub = lane >> 2;          // 0..15
    int csub = (lane & 3) * 8;     // 0,8,16,24
    const bf16* gA0 = A + (size_t)(m0 + wave * 32 + rsub) * K + csub;
    const bf16* gA1 = gA0 + (size_t)16 * K;
    const bf16* gB0 = Bt + (size_t)(n0 + wave * 32 + rsub) * K + csub;
    const bf16* gB1 = gB0 + (size_t)16 * K;
    bf16* lA0 = As + wave * 1024;
    bf16* lA1 = As + wave * 1024 + 512;
    bf16* lB0 = Bs + wave * 1024;
    bf16* lB1 = Bs + wave * 1024 + 512;

    for (int kt = 0; kt < K; kt += 32) {
        __builtin_amdgcn_global_load_lds(
            (const __attribute__((address_space(1))) void*)(gA0 + kt),
            (__attribute__((address_space(3))) void*)lA0, 16, 0, 0);
        __builtin_amdgcn_global_load_lds(
            (const __attribute__((address_space(1))) void*)(gA1 + kt),
            (__attribute__((address_space(3))) void*)lA1, 16, 0, 0);
        __builtin_amdgcn_global_load_lds(
            (const __attribute__((address_space(1))) void*)(gB0 + kt),
            (__attribute__((address_space(3))) void*)lB0, 16, 0, 0);
        __builtin_amdgcn_global_load_lds(
            (const __attribute__((address_space(1))) void*)(gB1 + kt),
            (__attribute__((address_space(3))) void*)lB1, 16, 0, 0);
        __syncthreads();

        short8 aF[4], bF[4];
#pragma unroll
        for (int i = 0; i < 4; i++)
            aF[i] = *(const short8*)(As + (wm * 64 + i * 16 + lr) * 32 + quad * 8);
#pragma unroll
        for (int j = 0; j < 4; j++)
            bF[j] = *(const short8*)(Bs + (wn * 64 + j * 16 + lr) * 32 + quad * 8);
#pragma unroll
        for (int i = 0; i < 4; i++)
#pragma unroll
            for (int j = 0; j < 4; j++)
                acc[i][j] = __builtin_amdgcn_mfma_f32_16x16x32_bf16(aF[i], bF[j], acc[i][j], 0, 0, 0);
        __syncthreads();
    }

    // epilogue: C/D layout col(n) = lane&15, row(m) = quad*4 + reg
#pragma unroll
    for (int i = 0; i < 4; i++) {
#pragma unroll
        for (int j = 0; j < 4; j++) {
            int gcn = n0 + wn * 64 + j * 16 + lr;
            float bv = bias[gcn];
#pragma unroll
            for (int reg = 0; reg < 4; reg++) {
                int gm = m0 + wm * 64 + i * 16 + quad * 4 + reg;
                float v = acc[i][j][reg] + bv;
                if (mode == 0) {
                    int t = gcn >> 11, hh = (gcn >> 7) & 15, d = gcn & 127;
                    int bb = gm >> 11, s = gm & 2047;
                    size_t hb = (size_t)(bb * NHEAD + hh);
                    if (t == 0) {
                        Qb[(hb * S_LEN + s) * HD + d] = __float2bfloat16(v * QSCALE);
                    } else if (t == 1) {
                        Kb[(hb * S_LEN + s) * HD + d] = __float2bfloat16(v);
                    } else {
                        Vt[(hb * HD + d) * S_LEN + s] = __float2bfloat16(v);
                    }
                } else {
                    C[(size_t)gm * N + gcn] = v;
                }
            }
        }
    }
}

// ---------------------------------------------------------------------------
// Flash attention (causal), balanced pairing. Grid (8, NHEAD, BATCH).
// Block p handles q-tiles p and 15-p (128 rows each) => 17 x 128-key
// iterations per block, uniform. 4 waves, wave handles 32 q-rows.
// Register prefetch of next K/V tile overlaps compute.
// ---------------------------------------------------------------------------
__global__ __launch_bounds__(256, 1) void attn_kernel(const bf16* __restrict__ Qb,
                                                      const bf16* __restrict__ Kb,
                                                      const bf16* __restrict__ Vt,
                                                      bf16* __restrict__ Obuf) {
    __shared__ __align__(16) bf16 Ks[128][136];    // [key][d]  pad 8
    __shared__ __align__(16) bf16 Vs[128][136];    // [d][key]  pad 8
    __shared__ __align__(16) bf16 Ps[4][32][144];  // per-wave P, pad to 144

    int tid = threadIdx.x;
    int wave = tid >> 6, lane = tid & 63;
    int quad = lane >> 4, lr = lane & 15;
    int p = blockIdx.x, head = blockIdx.y, b = blockIdx.z;
    size_t hb = (size_t)(b * NHEAD + head);
    const bf16* Qbase = Qb + hb * S_LEN * HD;
    const bf16* Kbase = Kb + hb * S_LEN * HD;
    const bf16* Vbase = Vt + hb * (size_t)HD * S_LEN;

    const floatx4 fzero = {0.f, 0.f, 0.f, 0.f};
    const float MASKV = -30000.f;

    // prefetch mapping: thread covers 8 x 16B chunks of the 128x128 tile
    int pr = 0, pc = 0;  // reused below
    ushort8 kpre[8], vpre[8];

    for (int sub = 0; sub < 2; sub++) {
        int qt = sub ? (15 - p) : p;
        int q0 = qt * 128;
        int niter = qt + 1;

        // Q fragments (pre-scaled): rows = q0 + wave*32 + mt*16 + lr
        short8 qF[2][4];
#pragma unroll
        for (int mt = 0; mt < 2; mt++)
#pragma unroll
            for (int kc = 0; kc < 4; kc++)
                qF[mt][kc] = *(const short8*)&Qbase[(size_t)(q0 + wave * 32 + mt * 16 + lr) * HD + kc * 32 + quad * 8];

        floatx4 Oacc[2][8];
        float mrow[2][4], lrow[2][4];
#pragma unroll
        for (int mt = 0; mt < 2; mt++) {
#pragma unroll
            for (int dn = 0; dn < 8; dn++) Oacc[mt][dn] = fzero;
#pragma unroll
            for (int r = 0; r < 4; r++) { mrow[mt][r] = -30000.f; lrow[mt][r] = 0.f; }
        }

        // prefetch tile 0
#pragma unroll
        for (int i = 0; i < 8; i++) {
            int idx = tid + i * 256;
            pr = idx >> 4; pc = (idx & 15) * 8;
            kpre[i] = *(const ushort8*)&Kbase[(size_t)pr * HD + pc];
            vpre[i] = *(const ushort8*)&Vbase[(size_t)pr * S_LEN + pc];
        }

        for (int kt = 0; kt < niter; kt++) {
            int ks0 = kt * 128;
            __syncthreads();   // previous iteration's LDS reads complete
#pragma unroll
            for (int i = 0; i < 8; i++) {
                int idx = tid + i * 256;
                pr = idx >> 4; pc = (idx & 15) * 8;
                *(ushort8*)&Ks[pr][pc] = kpre[i];
                *(ushort8*)&Vs[pr][pc] = vpre[i];
            }
            __syncthreads();
            if (kt + 1 < niter) {
                int ns0 = ks0 + 128;
#pragma unroll
                for (int i = 0; i < 8; i++) {
                    int idx = tid + i * 256;
                    pr = idx >> 4; pc = (idx & 15) * 8;
                    kpre[i] = *(const ushort8*)&Kbase[(size_t)(ns0 + pr) * HD + pc];
                    vpre[i] = *(const ushort8*)&Vbase[(size_t)pr * S_LEN + ns0 + pc];
                }
            }

            // ---- QK^T: scores for 128 keys ----
            floatx4 sc[2][8];
#pragma unroll
            for (int mt = 0; mt < 2; mt++)
#pragma unroll
                for (int nt = 0; nt < 8; nt++) sc[mt][nt] = fzero;
#pragma unroll
            for (int kc = 0; kc < 4; kc++)
#pragma unroll
                for (int nt = 0; nt < 8; nt++) {
                    short8 kf = *(const short8*)&Ks[nt * 16 + lr][kc * 32 + quad * 8];
#pragma unroll
                    for (int mt = 0; mt < 2; mt++)
                        sc[mt][nt] = __builtin_amdgcn_mfma_f32_16x16x32_bf16(qF[mt][kc], kf, sc[mt][nt], 0, 0, 0);
                }
            // causal mask only on the diagonal tile
            if (kt == qt) {
#pragma unroll
                for (int mt = 0; mt < 2; mt++)
#pragma unroll
                    for (int nt = 0; nt < 8; nt++)
#pragma unroll
                        for (int reg = 0; reg < 4; reg++) {
                            int qg = wave * 32 + mt * 16 + quad * 4 + reg;   // tile-local (q0==ks0)
                            int kg = nt * 16 + lr;
                            if (kg > qg) sc[mt][nt][reg] = MASKV;
                        }
            }
            // ---- online softmax ----
#pragma unroll
            for (int mt = 0; mt < 2; mt++) {
                float pm[4], alpha[4], rs[4];
#pragma unroll
                for (int r = 0; r < 4; r++) {
                    pm[r] = sc[mt][0][r];
#pragma unroll
                    for (int nt = 1; nt < 8; nt++) pm[r] = fmaxf(pm[r], sc[mt][nt][r]);
                }
#pragma unroll
                for (int off = 1; off < 16; off <<= 1)
#pragma unroll
                    for (int r = 0; r < 4; r++) pm[r] = fmaxf(pm[r], __shfl_xor(pm[r], off, 64));
#pragma unroll
                for (int r = 0; r < 4; r++) {
                    float mn = fmaxf(mrow[mt][r], pm[r]);
                    alpha[r] = __builtin_amdgcn_exp2f(mrow[mt][r] - mn);
                    mrow[mt][r] = mn;
                    rs[r] = 0.f;
                }
#pragma unroll
                for (int nt = 0; nt < 8; nt++)
#pragma unroll
                    for (int r = 0; r < 4; r++) {
                        float pv = __builtin_amdgcn_exp2f(sc[mt][nt][r] - mrow[mt][r]);
                        rs[r] += pv;
                        Ps[wave][mt * 16 + quad * 4 + r][nt * 16 + lr] = __float2bfloat16(pv);
                    }
#pragma unroll
                for (int off = 1; off < 16; off <<= 1)
#pragma unroll
                    for (int r = 0; r < 4; r++) rs[r] += __shfl_xor(rs[r], off, 64);
#pragma unroll
                for (int r = 0; r < 4; r++) lrow[mt][r] = lrow[mt][r] * alpha[r] + rs[r];
#pragma unroll
                for (int dn = 0; dn < 8; dn++)
#pragma unroll
                    for (int r = 0; r < 4; r++) Oacc[mt][dn][r] *= alpha[r];
            }
            // ---- PV ----
#pragma unroll
            for (int st = 0; st < 4; st++) {
                short8 aP[2];
#pragma unroll
                for (int mt = 0; mt < 2; mt++)
                    aP[mt] = *(const short8*)&Ps[wave][mt * 16 + lr][st * 32 + quad * 8];
#pragma unroll
                for (int dn = 0; dn < 8; dn++) {
                    short8 vf = *(const short8*)&Vs[dn * 16 + lr][st * 32 + quad * 8];
#pragma unroll
                    for (int mt = 0; mt < 2; mt++)
                        Oacc[mt][dn] = __builtin_amdgcn_mfma_f32_16x16x32_bf16(aP[mt], vf, Oacc[mt][dn], 0, 0, 0);
                }
            }
        }

        // epilogue: O /= l, store bf16 to Obuf[b*S+q][head*128+d]
#pragma unroll
        for (int mt = 0; mt < 2; mt++)
#pragma unroll
            for (int reg = 0; reg < 4; reg++) {
                float inv = 1.0f / lrow[mt][reg];
                int qg = q0 + wave * 32 + mt * 16 + quad * 4 + reg;
#pragma unroll
                for (int dn = 0; dn < 8; dn++) {
                    int d = dn * 16 + lr;
                    Obuf[((size_t)(b * S_LEN + qg)) * HIDDEN + head * HD + d] =
                        __float2bfloat16(Oacc[mt][dn][reg] * inv);
                }
            }
    }
}

// ---------------------------------------------------------------------------
extern "C" void kernel_launch(void* const* d_in, const int* in_sizes, int n_in,
                              void* d_out, int out_size, void* d_ws, size_t ws_size,
                              hipStream_t stream) {
    (void)in_sizes; (void)n_in; (void)out_size; (void)ws_size;
    const float* x    = (const float*)d_in[0];   // (2,2048,2048) fp32
    const float* Wqkv = (const float*)d_in[1];   // (2048,6144)  fp32
    const float* bqkv = (const float*)d_in[2];   // (6144,)      fp32
    const float* Wo   = (const float*)d_in[3];   // (2048,2048)  fp32
    const float* bo   = (const float*)d_in[4];   // (2048,)      fp32
    float* out = (float*)d_out;                  // (2,2048,2048) fp32

    // Workspace (bf16 elements), ~92 MB with aliasing
    bf16* ws = (bf16*)d_ws;
    bf16* Xb    = ws;                                   // 8.39M el
    bf16* Obuf  = ws;                                   // alias of Xb (dead after GEMM1)
    bf16* WqkvT = ws + (size_t)8388608;                 // 12.58M el
    bf16* WoT   = WqkvT;                                // alias (dead after GEMM1)
    bf16* Qb    = WqkvT + (size_t)12582912;
    bf16* Kb    = Qb + (size_t)8388608;
    bf16* Vt    = Kb + (size_t)8388608;

    cast_f32_bf16<<<4096, 256, 0, stream>>>(x, Xb);
    cast_transpose<<<dim3(192, 64), 256, 0, stream>>>(Wqkv, WqkvT, 2048, 6144);
    gemm_bt<<<dim3(48, 32), 256, 0, stream>>>(Xb, WqkvT, bqkv, nullptr,
                                              Qb, Kb, Vt, 4096, 6144, 2048, 0);
    cast_transpose<<<dim3(64, 64), 256, 0, stream>>>(Wo, WoT, 2048, 2048);
    attn_kernel<<<dim3(8, 16, 2), 256, 0, stream>>>(Qb, Kb, Vt, Obuf);
    gemm_bt<<<dim3(16, 32), 256, 0, stream>>>(Obuf, WoT, bo, out,
                                              nullptr, nullptr, nullptr, 4096, 2048, 2048, 1);
}